// Round 4
// baseline (746.629 us; speedup 1.0000x reference)
//
#include <hip/hip_runtime.h>

#define CROP_H 14
#define CROP_W 14
#define NBOX   512
#define CH     256
#define IMH    200
#define IMW    200
#define PLANE   (IMH * IMW)
#define NPOS    (CROP_H * CROP_W)          // 196
#define PER_BOX (CH * NPOS)                // 50176
#define NROWS   (2 * CROP_H)               // 28 staged rows (y0,y1 per gy)
#define LDS_STRIDE 204                     // floats per staged row (padded)

// Span-staged gather. One block = one (box, channel). The bilinear taps of a
// box lie in 28 image rows within a common x-span [min(x0), max(x1i)]
// (~140 64B lines avg = 9 KB) -- the SAME lines the scatter path touches,
// but staged with ~28 fully-coalesced wave-loads (one wave per row-span,
// lanes = consecutive float4) instead of ~46 scattered wave-loads that each
// serialize ~23 line-lookups in the TA/TCP. Gather then runs from LDS.
// Grid (box=x fastest, channel=y): resident blocks = all boxes x ~3
// channels (~4 MB window) so cross-box tap overlap stays L2/L3-resident.
__global__ __launch_bounds__(256, 7) void CropAndResize_60146722013533_kernel(
    const float* __restrict__ image,
    const float* __restrict__ boxes,
    const int*   __restrict__ box_idx,
    float*       __restrict__ out)
{
    const int n = blockIdx.x;          // box index (fastest dispatch dim)
    const int c = blockIdx.y;          // channel
    const int t = threadIdx.x;

    __shared__ float slds[NROWS][LDS_STRIDE];   // 22.85 KB
    __shared__ int   sy0[CROP_H], sy1[CROP_H], sx0[CROP_W], sx1[CROP_W];
    __shared__ float sly[CROP_H], slx[CROP_W];
    __shared__ int   svy[CROP_H], svx[CROP_W];
    __shared__ int   sb;

    // ---- per-box geometry (same arithmetic as verified r0 kernel) ----
    if (t < CROP_H + CROP_W) {
        const float by1 = boxes[n * 4 + 0];
        const float bx1 = boxes[n * 4 + 1];
        const float by2 = boxes[n * 4 + 2];
        const float bx2 = boxes[n * 4 + 3];
        if (t < CROP_H) {
            const int gy = t;
            float h_scale = (by2 - by1) * (float)(IMH - 1) / (float)(CROP_H - 1);
            float in_y = by1 * (float)(IMH - 1) + (float)gy * h_scale;
            svy[gy] = (in_y >= 0.0f && in_y <= (float)(IMH - 1)) ? 1 : 0;
            float yf = floorf(in_y);
            sly[gy] = in_y - yf;
            sy0[gy] = (int)fminf(fmaxf(yf, 0.0f), (float)(IMH - 1));
            sy1[gy] = (int)fminf(fmaxf(ceilf(in_y), 0.0f), (float)(IMH - 1));
        } else {
            const int gx = t - CROP_H;
            float w_scale = (bx2 - bx1) * (float)(IMW - 1) / (float)(CROP_W - 1);
            float in_x = bx1 * (float)(IMW - 1) + (float)gx * w_scale;
            svx[gx] = (in_x >= 0.0f && in_x <= (float)(IMW - 1)) ? 1 : 0;
            float xf = floorf(in_x);
            slx[gx] = in_x - xf;
            sx0[gx] = (int)fminf(fmaxf(xf, 0.0f), (float)(IMW - 1));
            sx1[gx] = (int)fminf(fmaxf(ceilf(in_x), 0.0f), (float)(IMW - 1));
        }
    }
    if (t == 0) sb = box_idx[n];
    __syncthreads();

    // ---- common x-span (broadcast LDS reads; every thread computes) ----
    int xlo = sx0[0], xhi = sx1[0];
    #pragma unroll
    for (int i = 1; i < CROP_W; ++i) {
        xlo = min(xlo, sx0[i]);
        xhi = max(xhi, sx1[i]);
    }
    const int f4lo  = xlo >> 2;
    const int nf4   = (xhi >> 2) - f4lo + 1;   // <= 50 always
    const int xbase = f4lo << 2;

    const float* __restrict__ pb =
        image + (size_t)(sb * CH + c) * (size_t)PLANE;

    // ---- stage: wave w loads staged rows w, w+4, ..., lanes = float4s ----
    {
        const int f4 = t & 63;
        const int w0 = t >> 6;
        if (f4 < nf4) {
            const float* src = pb + xbase + f4 * 4;
            #pragma unroll
            for (int rr = w0; rr < NROWS; rr += 4) {
                const int gyr = rr >> 1;
                const int row = (rr & 1) ? sy1[gyr] : sy0[gyr];
                float4 v;
                __builtin_memcpy(&v, src + row * IMW, 16);
                *(float4*)&slds[rr][f4 * 4] = v;
            }
        }
    }
    __syncthreads();

    // ---- gather + bilinear from LDS ----
    if (t < NPOS) {
        const int gy = t / CROP_W;
        const int gx = t - gy * CROP_W;
        const int x0  = sx0[gx] - xbase;
        const int x1i = sx1[gx] - xbase;
        const float ly = sly[gy];
        const float lx = slx[gx];

        const float tl = slds[2 * gy    ][x0];
        const float tr = slds[2 * gy    ][x1i];
        const float bl = slds[2 * gy + 1][x0];
        const float br = slds[2 * gy + 1][x1i];

        const float top = tl + (tr - tl) * lx;
        const float bot = bl + (br - bl) * lx;
        float val = top + (bot - top) * ly;
        if (!(svy[gy] & svx[gx])) val = 0.0f;

        __builtin_nontemporal_store(val, out + (size_t)n * PER_BOX + c * NPOS + t);
    }
}

extern "C" void kernel_launch(void* const* d_in, const int* in_sizes, int n_in,
                              void* d_out, int out_size, void* d_ws, size_t ws_size,
                              hipStream_t stream) {
    const float* image   = (const float*)d_in[0];
    const float* boxes   = (const float*)d_in[1];
    const int*   box_idx = (const int*)d_in[2];
    float* out = (float*)d_out;

    dim3 grid(NBOX, CH, 1);     // x = box (fastest), y = channel
    dim3 block(256, 1, 1);
    CropAndResize_60146722013533_kernel<<<grid, block, 0, stream>>>(image, boxes, box_idx, out);
}

// Round 5
// 484.507 us; speedup vs baseline: 1.5410x; 1.5410x over previous
//
#include <hip/hip_runtime.h>

#define CROP_H 14
#define CROP_W 14
#define NBOX   512
#define NIMG   8
#define CH     256
#define IMH    200
#define IMW    200
#define PLANE   (IMH * IMW)
#define NPOS    (CROP_H * CROP_W)          // 196
#define PER_BOX (CH * NPOS)                // 50176
#define CHUNK   512                        // elems per block (2 per thread)
#define NCHUNKS (PER_BOX / CHUNK)          // 98

// ---------------------------------------------------------------------------
// Prologue: build a box permutation with image<->XCD affinity.
// Linear wg id -> XCD is round-robin; grid.x = 512 is divisible by 8, so
// XCD = position % 8. Place boxes of image j at positions == j (mod 8):
// each XCD's L2 then serves taps of ONE image (~0.5 MB per chunk window,
// L2-resident) instead of all 8 images (~4 MB x 8, thrashing 4 MB L2).
// Overflow boxes (image count > 64) fill whatever slots remain.
// ---------------------------------------------------------------------------
__global__ __launch_bounds__(512) void CropAndResize_perm_kernel(
    const int* __restrict__ box_idx, int* __restrict__ perm)
{
    __shared__ int cnt[NIMG];
    __shared__ int nfree;
    __shared__ int freeslots[NBOX];
    const int t = threadIdx.x;             // one thread per box / per slot
    if (t < NIMG) cnt[t] = 0;
    if (t == 0) nfree = 0;
    __syncthreads();

    const int img = box_idx[t];
    const int r   = atomicAdd(&cnt[img], 1);      // rank within image group
    const int slot = (r < NBOX / NIMG) ? (img + NIMG * r) : -1;
    __syncthreads();

    // slot id t == (t&7) + 8*(t>>3): free iff its rank >= that image's count
    int myfree = -1;
    if ((t >> 3) >= cnt[t & 7]) {
        const int k = atomicAdd(&nfree, 1);
        freeslots[k] = t;
    }
    if (slot < 0) myfree = atomicAdd(&nfree, -1);  // claim from the top
    __syncthreads();

    if (slot >= 0) perm[slot] = t;
    else           perm[freeslots[myfree - 1]] = t;
}

// ---------------------------------------------------------------------------
// Main kernel: round-3 scatter structure (best measured, ~162us) with the
// box index indirected through perm[] for XCD affinity. 2 elems/thread,
// all 4 scattered 8B tap loads issued before use, nontemporal stores.
// ---------------------------------------------------------------------------
__global__ __launch_bounds__(256, 8) void CropAndResize_60146722013533_kernel(
    const float* __restrict__ image,
    const float* __restrict__ boxes,
    const int*   __restrict__ box_idx,
    const int*   __restrict__ perm,
    float*       __restrict__ out)
{
    const int n = perm[blockIdx.x];    // box index (XCD-affine placement)
    const int t = threadIdx.x;

    __shared__ int   sy0[CROP_H], sy1[CROP_H], sx0[CROP_W], sx1[CROP_W];
    __shared__ float sly[CROP_H], slx[CROP_W];
    __shared__ int   svy[CROP_H], svx[CROP_W];
    __shared__ int   sb;

    if (t < CROP_H + CROP_W) {
        const float by1 = boxes[n * 4 + 0];
        const float bx1 = boxes[n * 4 + 1];
        const float by2 = boxes[n * 4 + 2];
        const float bx2 = boxes[n * 4 + 3];
        if (t < CROP_H) {
            const int gy = t;
            float h_scale = (by2 - by1) * (float)(IMH - 1) / (float)(CROP_H - 1);
            float in_y = by1 * (float)(IMH - 1) + (float)gy * h_scale;
            svy[gy] = (in_y >= 0.0f && in_y <= (float)(IMH - 1)) ? 1 : 0;
            float yf = floorf(in_y);
            sly[gy] = in_y - yf;
            sy0[gy] = (int)fminf(fmaxf(yf, 0.0f), (float)(IMH - 1));
            sy1[gy] = (int)fminf(fmaxf(ceilf(in_y), 0.0f), (float)(IMH - 1));
        } else {
            const int gx = t - CROP_H;
            float w_scale = (bx2 - bx1) * (float)(IMW - 1) / (float)(CROP_W - 1);
            float in_x = bx1 * (float)(IMW - 1) + (float)gx * w_scale;
            svx[gx] = (in_x >= 0.0f && in_x <= (float)(IMW - 1)) ? 1 : 0;
            float xf = floorf(in_x);
            slx[gx] = in_x - xf;
            sx0[gx] = (int)fminf(fmaxf(xf, 0.0f), (float)(IMW - 1));
            sx1[gx] = (int)fminf(fmaxf(ceilf(in_x), 0.0f), (float)(IMW - 1));
        }
    }
    if (t == 0) sb = box_idx[n];
    __syncthreads();

    const int base = blockIdx.y * CHUNK;
    const float* __restrict__ img = image + (size_t)sb * CH * PLANE;
    float* __restrict__ ob = out + (size_t)n * PER_BOX + base + t;

    const int elem0 = base + t;
    const int elem1 = elem0 + 256;

    // elem 0 geometry
    const int c0  = elem0 / NPOS;
    const int r0  = elem0 - c0 * NPOS;
    const int gy0 = r0 / CROP_W;
    const int gx0 = r0 - gy0 * CROP_W;
    const int x0a = sx0[gx0];
    const int xb0 = (x0a < IMW - 2) ? x0a : (IMW - 2);
    const float* p0 = img + (size_t)c0 * PLANE;
    const float* rt0 = p0 + sy0[gy0] * IMW + xb0;
    const float* rb0 = p0 + sy1[gy0] * IMW + xb0;

    // elem 1 geometry
    const int c1  = elem1 / NPOS;
    const int r1  = elem1 - c1 * NPOS;
    const int gy1 = r1 / CROP_W;
    const int gx1 = r1 - gy1 * CROP_W;
    const int x1a = sx0[gx1];
    const int xb1 = (x1a < IMW - 2) ? x1a : (IMW - 2);
    const float* p1 = img + (size_t)c1 * PLANE;
    const float* rt1 = p1 + sy0[gy1] * IMW + xb1;
    const float* rb1 = p1 + sy1[gy1] * IMW + xb1;

    // issue all 4 scattered 8B loads before any use
    float2 vt0, vb0, vt1, vb1;
    __builtin_memcpy(&vt0, rt0, 8);
    __builtin_memcpy(&vb0, rb0, 8);
    __builtin_memcpy(&vt1, rt1, 8);
    __builtin_memcpy(&vb1, rb1, 8);

    // ---- elem 0 math ----
    {
        const int   x1i = sx1[gx0];
        const float ly  = sly[gy0];
        const float lx  = slx[gx0];
        const float tl = (x0a == xb0) ? vt0.x : vt0.y;
        const float tr = (x1i == xb0) ? vt0.x : vt0.y;
        const float bl = (x0a == xb0) ? vb0.x : vb0.y;
        const float br = (x1i == xb0) ? vb0.x : vb0.y;
        const float top = tl + (tr - tl) * lx;
        const float bot = bl + (br - bl) * lx;
        float val = top + (bot - top) * ly;
        if (!(svy[gy0] & svx[gx0])) val = 0.0f;
        __builtin_nontemporal_store(val, ob);
    }
    // ---- elem 1 math ----
    {
        const int   x1i = sx1[gx1];
        const float ly  = sly[gy1];
        const float lx  = slx[gx1];
        const float tl = (x1a == xb1) ? vt1.x : vt1.y;
        const float tr = (x1i == xb1) ? vt1.x : vt1.y;
        const float bl = (x1a == xb1) ? vb1.x : vb1.y;
        const float br = (x1i == xb1) ? vb1.x : vb1.y;
        const float top = tl + (tr - tl) * lx;
        const float bot = bl + (br - bl) * lx;
        float val = top + (bot - top) * ly;
        if (!(svy[gy1] & svx[gx1])) val = 0.0f;
        __builtin_nontemporal_store(val, ob + 256);
    }
}

extern "C" void kernel_launch(void* const* d_in, const int* in_sizes, int n_in,
                              void* d_out, int out_size, void* d_ws, size_t ws_size,
                              hipStream_t stream) {
    const float* image   = (const float*)d_in[0];
    const float* boxes   = (const float*)d_in[1];
    const int*   box_idx = (const int*)d_in[2];
    float* out  = (float*)d_out;
    int*   perm = (int*)d_ws;               // 512 ints in workspace

    CropAndResize_perm_kernel<<<dim3(1, 1, 1), dim3(NBOX, 1, 1), 0, stream>>>(
        box_idx, perm);

    dim3 grid(NBOX, NCHUNKS, 1);   // x = box (fastest), y = 512-elem chunk
    dim3 block(256, 1, 1);
    CropAndResize_60146722013533_kernel<<<grid, block, 0, stream>>>(
        image, boxes, box_idx, perm, out);
}